// Round 8
// baseline (327.011 us; speedup 1.0000x reference)
//
#include <hip/hip_runtime.h>

// LightGCN 2-layer propagation on MI355X — R17: high-occupancy single-pass
// scatcat (register-resident edges), R16 gather retained.
//
// R16 post-mortem: k_scatcat 73 us, VALUBusy 3.7%, Occupancy 27.5% — after
// concat blocks drain, only 512 edge blocks remain (2/CU, 8 waves/CU);
// two L2 passes with dependent load->atomic chains, nothing hides latency.
// R17: P=2048 edge blocks (8/CU, 100% occupancy in edge phase); each
// thread owns exactly ONE int4-pair (524288 thr >= 500000 int4s): load
// once, histogram from registers, reserve, scatter from the SAME
// registers — pass-2 edge re-read deleted.
// k_gat unchanged from R16 (PERM'd accumulator, int16 fixed-point).

#define NUM_USERS 100000
#define NUM_ITEMS 50000
#define N_NODES   150000
#define NUM_EDGES 2000000
#define EMB_D     64

#define BNODE  147                                 // nodes per bucket
#define NBUCK  1024                                // 4 blocks/CU at 512 thr
#define MAGIC  29217465u                           // ceil(2^32/147), exact for n<150016
#define P      2048                                // edge blocks (1 int4/thread)
#define E4     (NUM_EDGES / 4)                     // 500000 int4 per edge stream
#define CAP    5120                                // bucket region capacity
#define CSTRIDE 16                                 // cursor padding (64 B)
#define CURN   (NBUCK * CSTRIDE)                   // 16384 ints

#define ASTRIDE 65                                 // LDS acc row stride (ints)
#define ACCN    (BNODE * ASTRIDE)                  // 9555 ints = 38.2 KB
#define PERM(c) ((((c) & 7) << 3) | ((c) >> 3))    // bijective 0..63

#define CPYB   1024                                // concat-convert blocks
#define H8CNT  (N_NODES * (EMB_D / 8))             // 1.2M 16-byte chunks
#define UF4    (NUM_USERS * (EMB_D / 4))           // user float4 count

struct alignas(16) s8vec { short s[8]; };          // 8 int16 = 16 B

__device__ __forceinline__ unsigned buck(unsigned n) {
    return (unsigned)(((unsigned long long)n * MAGIC) >> 32);
}

__device__ __forceinline__ short q12(float x) {
    return (short)__float2int_rn(fminf(fmaxf(x * 4096.f, -32600.f), 32600.f));
}

// ---- 0) zero the reservation cursors ----
__global__ __launch_bounds__(1024) void k_zero(int* __restrict__ cur) {
    int i = blockIdx.x * 1024 + threadIdx.x;
    if (i < CURN) cur[i] = 0;
}

// ---- A) fused build: reg-resident histogram -> reserve -> scatter ----
__global__ __launch_bounds__(256) void k_scatcat(const int* __restrict__ eidx,
                                                 int* __restrict__ cur,
                                                 unsigned* __restrict__ entries,
                                                 const float4* __restrict__ user4,
                                                 const float4* __restrict__ item4,
                                                 s8vec* __restrict__ tab) {
    int g = blockIdx.x, tid = threadIdx.x;
    if (g >= P) {
        // concat: tab rows [0,NUM_USERS) = user, [NUM_USERS,N) = item (q12)
        int i = (g - P) * 256 + tid;
        const int stride = CPYB * 256;
        for (; i < H8CNT; i += stride) {
            const float4* s = (i * 2 < UF4) ? (user4 + (size_t)i * 2)
                                            : (item4 + ((size_t)i * 2 - UF4));
            float4 a = s[0], b = s[1];
            s8vec o;
            o.s[0] = q12(a.x); o.s[1] = q12(a.y); o.s[2] = q12(a.z); o.s[3] = q12(a.w);
            o.s[4] = q12(b.x); o.s[5] = q12(b.y); o.s[6] = q12(b.z); o.s[7] = q12(b.w);
            tab[i] = o;
        }
        return;
    }

    __shared__ int lh[NBUCK];                      // hist, then running cursor
    for (int b = tid; b < NBUCK; b += 256) lh[b] = 0;

    int j = g * 256 + tid;                         // one int4-pair per thread
    bool act = j < E4;
    int rr[4] = {0, 0, 0, 0}, cc[4] = {0, 0, 0, 0};
    if (act) {
        int4 a = ((const int4*)eidx)[j];
        int4 b = ((const int4*)(eidx + NUM_EDGES))[j];
        rr[0] = a.x; rr[1] = a.y; rr[2] = a.z; rr[3] = a.w;
        cc[0] = b.x; cc[1] = b.y; cc[2] = b.z; cc[3] = b.w;
    }
    __syncthreads();

    // pass 1: histogram from registers
    if (act) {
        #pragma unroll
        for (int q = 0; q < 4; ++q) {
            atomicAdd(&lh[buck((unsigned)rr[q])], 1);
            atomicAdd(&lh[buck((unsigned)cc[q])], 1);
        }
    }
    __syncthreads();

    // reserve a chunk per bucket in its fixed region; lh becomes the cursor
    for (int b = tid; b < NBUCK; b += 256) {
        int h = lh[b];
        int base = (h > 0) ? atomicAdd(&cur[b * CSTRIDE], h) : 0;
        lh[b] = base;
    }
    __syncthreads();

    // pass 2: scatter from the same registers (no edge re-read)
    if (act) {
        #pragma unroll
        for (int q = 0; q < 4; ++q) {
            unsigned r = (unsigned)rr[q], c = (unsigned)cc[q];
            unsigned br = buck(r), bc = buck(c);
            unsigned lr = r - br * BNODE, lc = c - bc * BNODE;
            int p = atomicAdd(&lh[br], 1);
            if (p < CAP) entries[(size_t)br * CAP + p] = (lr << 18) | c;
            int p2 = atomicAdd(&lh[bc], 1);
            if (p2 < CAP) entries[(size_t)bc * CAP + p2] = (lc << 18) | r;
        }
    }
}

// ---- B) entry-centric bucket gather, int32 LDS accumulation ----
// Block = one bucket (147 nodes). 8 lanes per entry: lane s loads 16 B
// (cols s*8..s*8+7, int16) of the neighbor's row; ds_add into permuted
// accumulator layout: col c of node loc lives at loc*ASTRIDE + PERM(c),
// so instr i's 64 lanes hit addresses loc*65 + 8i + s (8 consecutive
// banks per entry). 1-deep software pipeline on (entry, row).
// MODE 0: write inter16 (int16, scale 2^9). MODE 1: write fp32 out.
template <int MODE>
__global__ __launch_bounds__(512) void k_gat(const unsigned* __restrict__ entries,
                                             const int* __restrict__ cur,
                                             const s8vec* __restrict__ tv,
                                             void* __restrict__ dst) {
    __shared__ int acc[ACCN];                      // 38.2 KB
    int b = blockIdx.x, tid = threadIdx.x;

    for (int i = tid; i < ACCN; i += 512) acc[i] = 0;

    int cnt = min(cur[b * CSTRIDE], CAP);
    const unsigned* eb = entries + (size_t)b * CAP;
    __syncthreads();

    int s = tid & 7;                               // col group 0..7
    int kk = tid >> 3;                             // entry slot 0..63

    int k = kk;
    if (k < cnt) {
        unsigned e = eb[k];
        s8vec r = tv[(size_t)(e & 0x3FFFFu) * 8 + s];
        for (k += 64; k < cnt; k += 64) {
            unsigned e2 = eb[k];                   // prefetch next entry
            s8vec r2 = tv[(size_t)(e2 & 0x3FFFFu) * 8 + s];   // next row
            int cb = (int)(e >> 18) * ASTRIDE + s;
            atomicAdd(&acc[cb +  0], (int)r.s[0]);
            atomicAdd(&acc[cb +  8], (int)r.s[1]);
            atomicAdd(&acc[cb + 16], (int)r.s[2]);
            atomicAdd(&acc[cb + 24], (int)r.s[3]);
            atomicAdd(&acc[cb + 32], (int)r.s[4]);
            atomicAdd(&acc[cb + 40], (int)r.s[5]);
            atomicAdd(&acc[cb + 48], (int)r.s[6]);
            atomicAdd(&acc[cb + 56], (int)r.s[7]);
            e = e2; r = r2;
        }
        int cb = (int)(e >> 18) * ASTRIDE + s;
        atomicAdd(&acc[cb +  0], (int)r.s[0]);
        atomicAdd(&acc[cb +  8], (int)r.s[1]);
        atomicAdd(&acc[cb + 16], (int)r.s[2]);
        atomicAdd(&acc[cb + 24], (int)r.s[3]);
        atomicAdd(&acc[cb + 32], (int)r.s[4]);
        atomicAdd(&acc[cb + 40], (int)r.s[5]);
        atomicAdd(&acc[cb + 48], (int)r.s[6]);
        atomicAdd(&acc[cb + 56], (int)r.s[7]);
    }
    __syncthreads();

    int nbase = b * BNODE;
    if constexpr (MODE == 0) {
        // inter16 = round(acc / 16): scale 2^9; pack 2 cols per int
        int* o = (int*)dst;
        for (int idx = tid; idx < BNODE * 32; idx += 512) {
            int loc = idx >> 5, cp = idx & 31;
            int node = nbase + loc;
            if (node < N_NODES) {
                int a0 = loc * ASTRIDE;
                int c0 = cp * 2, c1 = cp * 2 + 1;
                int v0 = (acc[a0 + PERM(c0)] + 8) >> 4;
                int v1 = (acc[a0 + PERM(c1)] + 8) >> 4;
                o[(size_t)node * 32 + cp] = (v0 & 0xFFFF) | (v1 << 16);
            }
        }
    } else {
        // out = acc * 0.5 / 2^9 = acc / 1024
        float* o = (float*)dst;
        for (int idx = tid; idx < BNODE * 64; idx += 512) {
            int loc = idx >> 6, col = idx & 63;
            int node = nbase + loc;
            if (node < N_NODES)
                o[(size_t)node * 64 + col] =
                    (float)acc[loc * ASTRIDE + PERM(col)] * (1.f / 1024.f);
        }
    }
}

extern "C" void kernel_launch(void* const* d_in, const int* in_sizes, int n_in,
                              void* d_out, int out_size, void* d_ws, size_t ws_size,
                              hipStream_t stream) {
    const int*   eidx = (const int*)d_in[0];     // [2, NUM_EDGES]
    const float* user = (const float*)d_in[1];   // [NUM_USERS, 64]
    const float* item = (const float*)d_in[2];   // [NUM_ITEMS, 64]
    float*       out  = (float*)d_out;           // [N_NODES, 64] fp32

    // int16 concat table lives in out[0 .. 19.2 MB) — dead once layer 2 writes.
    s8vec* tab16 = (s8vec*)out;

    char* ws = (char*)d_ws;
    size_t off = 0;
    auto alloc = [&](size_t bytes) {
        char* p = ws + off;
        off += (bytes + 255) & ~(size_t)255;
        return p;
    };
    unsigned* entries = (unsigned*)alloc((size_t)NBUCK * CAP * sizeof(unsigned));   // 21 MB
    s8vec*    inter16 = (s8vec*)alloc((size_t)N_NODES * 8 * sizeof(s8vec));         // 19.2 MB
    int*      cur     = (int*)alloc((size_t)CURN * sizeof(int));                    // 64 KB

    k_zero<<<(CURN + 1023) / 1024, 1024, 0, stream>>>(cur);
    k_scatcat<<<P + CPYB, 256, 0, stream>>>(eidx, cur, entries,
                                            (const float4*)user,
                                            (const float4*)item, tab16);
    k_gat<0><<<NBUCK, 512, 0, stream>>>(entries, cur, tab16, inter16);
    k_gat<1><<<NBUCK, 512, 0, stream>>>(entries, cur, inter16, out);
}

// Round 9
// 269.252 us; speedup vs baseline: 1.2145x; 1.2145x over previous
//
#include <hip/hip_runtime.h>

// LightGCN 2-layer propagation on MI355X — R18: 1024-thread build blocks.
//
// R17 post-mortem: k_scatcat 73 -> 120 us DESPITE occupancy 27->80%.
// Cause: per-bucket range-reservation atomics serialize per cursor
// ADDRESS; chain length = edge-block count (R16: 512, R17: 2048 -> ~1780
// same-address atomics/cursor ~ 90 us). More waves can't hide a serial
// same-address chain. R18 minimizes blocks while maximizing waves/block:
//   1024-thr edge blocks, PE=489 (one int4-pair/thread, reg-resident
//   single pass) -> 489-long reservation chains (< R16's 512) AND
//   16 waves/block x 2 blocks/CU = 100% occupancy in the edge phase.
//   Reservation = exactly one atomic per thread (tid==bucket, no loop).
// k_gat unchanged (PERM'd int32 accumulator, int16 fixed-point tables).

#define NUM_USERS 100000
#define NUM_ITEMS 50000
#define N_NODES   150000
#define NUM_EDGES 2000000
#define EMB_D     64

#define BNODE  147                                 // nodes per bucket
#define NBUCK  1024                                // = build block size
#define MAGIC  29217465u                           // ceil(2^32/147), exact for n<150016
#define E4     (NUM_EDGES / 4)                     // 500000 int4 per edge stream
#define PE     ((E4 + 1023) / 1024)                // 489 edge blocks
#define CAP    5120                                // bucket region capacity
#define CSTRIDE 16                                 // cursor padding (64 B)
#define CURN   (NBUCK * CSTRIDE)                   // 16384 ints

#define ASTRIDE 65                                 // LDS acc row stride (ints)
#define ACCN    (BNODE * ASTRIDE)                  // 9555 ints = 38.2 KB
#define PERM(c) ((((c) & 7) << 3) | ((c) >> 3))    // bijective 0..63

#define CPYB   512                                 // concat blocks (1024 thr)
#define H8CNT  (N_NODES * (EMB_D / 8))             // 1.2M 16-byte chunks
#define UF4    (NUM_USERS * (EMB_D / 4))           // user float4 count

struct alignas(16) s8vec { short s[8]; };          // 8 int16 = 16 B

__device__ __forceinline__ unsigned buck(unsigned n) {
    return (unsigned)(((unsigned long long)n * MAGIC) >> 32);
}

__device__ __forceinline__ short q12(float x) {
    return (short)__float2int_rn(fminf(fmaxf(x * 4096.f, -32600.f), 32600.f));
}

// ---- 0) zero the reservation cursors ----
__global__ __launch_bounds__(1024) void k_zero(int* __restrict__ cur) {
    int i = blockIdx.x * 1024 + threadIdx.x;
    if (i < CURN) cur[i] = 0;
}

// ---- A) fused build: reg-resident histogram -> reserve -> scatter ----
__global__ __launch_bounds__(1024) void k_scatcat(const int* __restrict__ eidx,
                                                  int* __restrict__ cur,
                                                  unsigned* __restrict__ entries,
                                                  const float4* __restrict__ user4,
                                                  const float4* __restrict__ item4,
                                                  s8vec* __restrict__ tab) {
    int g = blockIdx.x, tid = threadIdx.x;
    if (g >= PE) {
        // concat: tab rows [0,NUM_USERS) = user, [NUM_USERS,N) = item (q12)
        int i = (g - PE) * 1024 + tid;
        const int stride = CPYB * 1024;
        for (; i < H8CNT; i += stride) {
            const float4* s = (i * 2 < UF4) ? (user4 + (size_t)i * 2)
                                            : (item4 + ((size_t)i * 2 - UF4));
            float4 a = s[0], b = s[1];
            s8vec o;
            o.s[0] = q12(a.x); o.s[1] = q12(a.y); o.s[2] = q12(a.z); o.s[3] = q12(a.w);
            o.s[4] = q12(b.x); o.s[5] = q12(b.y); o.s[6] = q12(b.z); o.s[7] = q12(b.w);
            tab[i] = o;
        }
        return;
    }

    __shared__ int lh[NBUCK];                      // hist, then running cursor
    lh[tid] = 0;                                   // 1024 threads == NBUCK

    int j = g * 1024 + tid;                        // one int4-pair per thread
    bool act = j < E4;
    int rr[4] = {0, 0, 0, 0}, cc[4] = {0, 0, 0, 0};
    if (act) {
        int4 a = ((const int4*)eidx)[j];
        int4 b = ((const int4*)(eidx + NUM_EDGES))[j];
        rr[0] = a.x; rr[1] = a.y; rr[2] = a.z; rr[3] = a.w;
        cc[0] = b.x; cc[1] = b.y; cc[2] = b.z; cc[3] = b.w;
    }
    __syncthreads();

    // pass 1: histogram from registers
    if (act) {
        #pragma unroll
        for (int q = 0; q < 4; ++q) {
            atomicAdd(&lh[buck((unsigned)rr[q])], 1);
            atomicAdd(&lh[buck((unsigned)cc[q])], 1);
        }
    }
    __syncthreads();

    // reserve: one bucket per thread, single global atomic
    {
        int h = lh[tid];
        int base = (h > 0) ? atomicAdd(&cur[tid * CSTRIDE], h) : 0;
        lh[tid] = base;
    }
    __syncthreads();

    // pass 2: scatter from the same registers (no edge re-read)
    if (act) {
        #pragma unroll
        for (int q = 0; q < 4; ++q) {
            unsigned r = (unsigned)rr[q], c = (unsigned)cc[q];
            unsigned br = buck(r), bc = buck(c);
            unsigned lr = r - br * BNODE, lc = c - bc * BNODE;
            int p = atomicAdd(&lh[br], 1);
            if (p < CAP) entries[(size_t)br * CAP + p] = (lr << 18) | c;
            int p2 = atomicAdd(&lh[bc], 1);
            if (p2 < CAP) entries[(size_t)bc * CAP + p2] = (lc << 18) | r;
        }
    }
}

// ---- B) entry-centric bucket gather, int32 LDS accumulation ----
// Block = one bucket (147 nodes). 8 lanes per entry: lane s loads 16 B
// (cols s*8..s*8+7, int16) of the neighbor's row; ds_add into permuted
// accumulator layout: col c of node loc lives at loc*ASTRIDE + PERM(c),
// so instr i's 64 lanes hit addresses loc*65 + 8i + s (8 consecutive
// banks per entry). 1-deep software pipeline on (entry, row).
// MODE 0: write inter16 (int16, scale 2^9). MODE 1: write fp32 out.
template <int MODE>
__global__ __launch_bounds__(512) void k_gat(const unsigned* __restrict__ entries,
                                             const int* __restrict__ cur,
                                             const s8vec* __restrict__ tv,
                                             void* __restrict__ dst) {
    __shared__ int acc[ACCN];                      // 38.2 KB
    int b = blockIdx.x, tid = threadIdx.x;

    for (int i = tid; i < ACCN; i += 512) acc[i] = 0;

    int cnt = min(cur[b * CSTRIDE], CAP);
    const unsigned* eb = entries + (size_t)b * CAP;
    __syncthreads();

    int s = tid & 7;                               // col group 0..7
    int kk = tid >> 3;                             // entry slot 0..63

    int k = kk;
    if (k < cnt) {
        unsigned e = eb[k];
        s8vec r = tv[(size_t)(e & 0x3FFFFu) * 8 + s];
        for (k += 64; k < cnt; k += 64) {
            unsigned e2 = eb[k];                   // prefetch next entry
            s8vec r2 = tv[(size_t)(e2 & 0x3FFFFu) * 8 + s];   // next row
            int cb = (int)(e >> 18) * ASTRIDE + s;
            atomicAdd(&acc[cb +  0], (int)r.s[0]);
            atomicAdd(&acc[cb +  8], (int)r.s[1]);
            atomicAdd(&acc[cb + 16], (int)r.s[2]);
            atomicAdd(&acc[cb + 24], (int)r.s[3]);
            atomicAdd(&acc[cb + 32], (int)r.s[4]);
            atomicAdd(&acc[cb + 40], (int)r.s[5]);
            atomicAdd(&acc[cb + 48], (int)r.s[6]);
            atomicAdd(&acc[cb + 56], (int)r.s[7]);
            e = e2; r = r2;
        }
        int cb = (int)(e >> 18) * ASTRIDE + s;
        atomicAdd(&acc[cb +  0], (int)r.s[0]);
        atomicAdd(&acc[cb +  8], (int)r.s[1]);
        atomicAdd(&acc[cb + 16], (int)r.s[2]);
        atomicAdd(&acc[cb + 24], (int)r.s[3]);
        atomicAdd(&acc[cb + 32], (int)r.s[4]);
        atomicAdd(&acc[cb + 40], (int)r.s[5]);
        atomicAdd(&acc[cb + 48], (int)r.s[6]);
        atomicAdd(&acc[cb + 56], (int)r.s[7]);
    }
    __syncthreads();

    int nbase = b * BNODE;
    if constexpr (MODE == 0) {
        // inter16 = round(acc / 16): scale 2^9; pack 2 cols per int
        int* o = (int*)dst;
        for (int idx = tid; idx < BNODE * 32; idx += 512) {
            int loc = idx >> 5, cp = idx & 31;
            int node = nbase + loc;
            if (node < N_NODES) {
                int a0 = loc * ASTRIDE;
                int c0 = cp * 2, c1 = cp * 2 + 1;
                int v0 = (acc[a0 + PERM(c0)] + 8) >> 4;
                int v1 = (acc[a0 + PERM(c1)] + 8) >> 4;
                o[(size_t)node * 32 + cp] = (v0 & 0xFFFF) | (v1 << 16);
            }
        }
    } else {
        // out = acc * 0.5 / 2^9 = acc / 1024
        float* o = (float*)dst;
        for (int idx = tid; idx < BNODE * 64; idx += 512) {
            int loc = idx >> 6, col = idx & 63;
            int node = nbase + loc;
            if (node < N_NODES)
                o[(size_t)node * 64 + col] =
                    (float)acc[loc * ASTRIDE + PERM(col)] * (1.f / 1024.f);
        }
    }
}

extern "C" void kernel_launch(void* const* d_in, const int* in_sizes, int n_in,
                              void* d_out, int out_size, void* d_ws, size_t ws_size,
                              hipStream_t stream) {
    const int*   eidx = (const int*)d_in[0];     // [2, NUM_EDGES]
    const float* user = (const float*)d_in[1];   // [NUM_USERS, 64]
    const float* item = (const float*)d_in[2];   // [NUM_ITEMS, 64]
    float*       out  = (float*)d_out;           // [N_NODES, 64] fp32

    // int16 concat table lives in out[0 .. 19.2 MB) — dead once layer 2 writes.
    s8vec* tab16 = (s8vec*)out;

    char* ws = (char*)d_ws;
    size_t off = 0;
    auto alloc = [&](size_t bytes) {
        char* p = ws + off;
        off += (bytes + 255) & ~(size_t)255;
        return p;
    };
    unsigned* entries = (unsigned*)alloc((size_t)NBUCK * CAP * sizeof(unsigned));   // 21 MB
    s8vec*    inter16 = (s8vec*)alloc((size_t)N_NODES * 8 * sizeof(s8vec));         // 19.2 MB
    int*      cur     = (int*)alloc((size_t)CURN * sizeof(int));                    // 64 KB

    k_zero<<<(CURN + 1023) / 1024, 1024, 0, stream>>>(cur);
    k_scatcat<<<PE + CPYB, 1024, 0, stream>>>(eidx, cur, entries,
                                              (const float4*)user,
                                              (const float4*)item, tab16);
    k_gat<0><<<NBUCK, 512, 0, stream>>>(entries, cur, tab16, inter16);
    k_gat<1><<<NBUCK, 512, 0, stream>>>(entries, cur, inter16, out);
}